// Round 12
// baseline (3001.076 us; speedup 1.0000x reference)
//
#include <hip/hip_runtime.h>

constexpr int B_ = 16, L_ = 2048, C_ = 256, K_ = 64, INNER_ = 4096;
constexpr int NCH = 32;          // L-chunks (RPB=64)
constexpr int RPB = 64;          // rows per k_em block
constexpr int GRID_EM = 512;     // 2 blocks/CU x 256 CUs (capacity-exact)
#define EPSF 1e-6f

typedef __attribute__((ext_vector_type(8)))  short bf16x8;
typedef __attribute__((ext_vector_type(4)))  float f32x4;
typedef __attribute__((ext_vector_type(16))) float f32x16;
typedef _Float16 f16;
typedef __attribute__((ext_vector_type(8))) _Float16 f16x8;
typedef __attribute__((ext_vector_type(4))) _Float16 f16x4;

__device__ __forceinline__ unsigned short f2bf(float f) {
  union { float f; unsigned u; } v; v.f = f;
  unsigned r = v.u + 0x7fffu + ((v.u >> 16) & 1u);   // RNE
  return (unsigned short)(r >> 16);
}

__device__ __forceinline__ void gload16(const void* src, void* lds) {
  __builtin_amdgcn_global_load_lds(
      (const __attribute__((address_space(1))) unsigned*)src,
      (__attribute__((address_space(3))) unsigned*)lds, 16, 0, 0);
}

// device-scope grid barrier (monotone counter; reset per launch by memset).
// Bounded spin: converts a residency bug into wrong-answer, not a hang.
__device__ __forceinline__ void gbar(unsigned* bar, unsigned tgt) {
  __syncthreads();                       // all waves' stores vmcnt-drained
  if (threadIdx.x == 0) {
    __threadfence();                     // release: L2 writeback to coherent pt
    __hip_atomic_fetch_add(bar, 1u, __ATOMIC_ACQ_REL, __HIP_MEMORY_SCOPE_AGENT);
    unsigned v = __hip_atomic_load(bar, __ATOMIC_ACQUIRE, __HIP_MEMORY_SCOPE_AGENT);
    long guard = 0;
    while (v < tgt && guard < (1L << 24)) {
      __builtin_amdgcn_s_sleep(4);
      v = __hip_atomic_load(bar, __ATOMIC_ACQUIRE, __HIP_MEMORY_SCOPE_AGENT);
      ++guard;
    }
    __threadfence();                     // acquire: invalidate CU caches
  }
  __syncthreads();
}

// ---------------------------------------------------------------- k_prext
// merged k_pre (bid<4096) + k_xT (bid>=4096)
__global__ __launch_bounds__(256) void k_prext(
    const float* __restrict__ x,
    const float* __restrict__ w1, const float* __restrict__ w2,
    const float* __restrict__ gamma, const float* __restrict__ beta,
    const float* __restrict__ bmean, const float* __restrict__ bvar,
    const float* __restrict__ b1, const float* __restrict__ mu0,
    unsigned short* __restrict__ w1fr, unsigned short* __restrict__ w2fr,
    f16* __restrict__ bnshH, f16* __restrict__ muF,
    f16* __restrict__ xf, f16* __restrict__ xTf)
{
  __shared__ float ts[64][65];
  int bid = blockIdx.x, t = threadIdx.x;
  if (bid < 4096) {
    int i = bid * 256 + t;     // covers 1048576
    if (i < INNER_ * C_) {
      int j = i & 7, l31 = (i >> 3) & 31;
      { // w1fr: l5 bit 8, ks bits 9-12, ih bit 13, ic bits 14+ (sigma k-perm)
        int l5 = (i >> 8) & 1, ks = (i >> 9) & 15, ih = (i >> 13) & 1, ic = i >> 14;
        int r1 = ic * 64 + ih * 32 + l31;
        int c1 = ks * 16 + 4 * l5 + 8 * (j >> 2) + (j & 3);
        float sc = gamma[r1] * rsqrtf(bvar[r1] + 1e-5f);
        w1fr[i] = f2bf(w1[(size_t)r1 * C_ + c1] * sc);
      }
      { // w2fr: ot bits 8-10, l5 bit 11, g bits 12+ (sigma k-perm)
        int ot = (i >> 8) & 7, l5 = (i >> 11) & 1, g = i >> 12;
        int o = ot * 32 + l31;
        int ii = g * 16 + 4 * l5 + 8 * (j >> 2) + (j & 3);
        w2fr[i] = f2bf(w2[(size_t)o * INNER_ + ii]);
      }
    }
    if (i < B_ * K_ * C_) muF[i] = (f16)mu0[i & (K_ * C_ - 1)];
    if (i < INNER_) {
      float sc = gamma[i] * rsqrtf(bvar[i] + 1e-5f);
      bnshH[i] = (f16)fmaf(b1[i] - bmean[i], sc, beta[i]);
    }
  } else {
    int b2 = bid - 4096;
    int l0 = (b2 & 31) * 64, c0 = ((b2 >> 5) & 3) * 64, b = b2 >> 7;
    for (int p = 0; p < 16; ++p) {
      int e = t + p * 256, i = e >> 6, j = e & 63;
      float vv = x[((size_t)b * L_ + l0 + i) * C_ + c0 + j];
      ts[i][j] = vv;
      xf[((size_t)b * L_ + l0 + i) * C_ + c0 + j] = (f16)vv;
    }
    __syncthreads();
    for (int p = 0; p < 16; ++p) {
      int e = t + p * 256, i = e >> 6, j = e & 63;
      xTf[((size_t)b * C_ + c0 + i) * L_ + l0 + j] = (f16)ts[j][i];
    }
  }
}

// ---------------------------------------------------------------- k_emfused
// persistent: 10 x (EM step + mufin) + new_z/attn, one launch.
// block = (b = bid>>5, chn = bid&31); xfr regs + xtile LDS live across steps.
__global__ __launch_bounds__(256, 2) void k_emfused(
    const f16* __restrict__ xf,    // [B][L][C]
    const f16* __restrict__ xTf,   // [B][C][L]
    f16* __restrict__ muF,         // [B][K][C] state
    f16* __restrict__ muT,         // [B][C][K] out (last)
    f16* __restrict__ zA,          // [BL][64] out (step 10 z)
    float* __restrict__ cp,        // [NCH][B*K] scratch
    f16* __restrict__ part,        // [NCH][B][K][C] scratch
    float* __restrict__ zsA,       // [B*K] out (last colsum)
    float* __restrict__ outmu,     // d_out mu (f32)
    float* __restrict__ attnout,   // d_out attn [B][1][K][L]
    unsigned* __restrict__ bar)
{
  __shared__ f16 mu_s[K_ * C_];     // 32KB, slot ^ (k&15)
  __shared__ f16 zT_s[K_ * RPB];    // 8KB,  slot ^ (k&7)
  __shared__ f16 xtile[C_ * RPB];   // 32KB, slot ^ (c&7)
  __shared__ float cpart[4][K_];

  int bid = blockIdx.x;
  int chn = bid & 31, b = bid >> 5, l0 = chn * RPB;
  int t = threadIdx.x, w = t >> 6, lane = t & 63, l15 = lane & 15, g = lane >> 4;
  unsigned ph = 0;

  // ---- prologue (once): xf rows -> regs; xT tile -> LDS
  f16x8 xfr[8];
  const f16* xr = xf + ((size_t)b * L_ + l0 + w * 16 + l15) * C_ + g * 8;
#pragma unroll
  for (int ck = 0; ck < 8; ++ck) xfr[ck] = *(const f16x8*)(xr + ck * 32);
#pragma unroll
  for (int q = 0; q < 8; ++q) {
    int s = q * 256 + t, c = s >> 3, sl = s & 7;
    gload16(xTf + (size_t)(b * C_ + c) * L_ + l0 + ((sl ^ (c & 7)) << 3), xtile + s * 8);
  }

  float z[4][4];

  for (int st = 0; st < 10; ++st) {
    // ---- stage mu (changes every step)
#pragma unroll
    for (int q = 0; q < 8; ++q) {
      int s = q * 256 + t, k = s >> 5, sl = s & 31;
      gload16(muF + (size_t)b * (K_ * C_) + k * C_ + ((sl ^ (k & 15)) << 3), mu_s + s * 8);
    }
    asm volatile("s_waitcnt vmcnt(0)" ::: "memory");
    __syncthreads();

    // ---- phase1: S^T[k][tok], wave w owns tok tile w (16 toks)
    f32x4 acc[4];
#pragma unroll
    for (int mt = 0; mt < 4; ++mt)
#pragma unroll
      for (int j = 0; j < 4; ++j) acc[mt][j] = 0.f;
#pragma unroll
    for (int ck = 0; ck < 8; ++ck) {
#pragma unroll
      for (int mt = 0; mt < 4; ++mt) {
        f16x8 a = *(const f16x8*)(mu_s + (mt * 16 + l15) * C_ + (((ck * 4 + g) ^ l15) << 3));
        acc[mt] = __builtin_amdgcn_mfma_f32_16x16x32_f16(a, xfr[ck], acc[mt], 0, 0, 0);
      }
    }

    // ---- phase2: softmax over k
    {
      float mx = acc[0][0];
#pragma unroll
      for (int mt = 0; mt < 4; ++mt)
#pragma unroll
        for (int jj = 0; jj < 4; ++jj) mx = fmaxf(mx, acc[mt][jj]);
      mx = fmaxf(mx, __shfl_xor(mx, 16, 64));
      mx = fmaxf(mx, __shfl_xor(mx, 32, 64));
      float sm = 0.f;
#pragma unroll
      for (int mt = 0; mt < 4; ++mt)
#pragma unroll
        for (int jj = 0; jj < 4; ++jj) {
          float e = __expf(acc[mt][jj] - mx);
          z[mt][jj] = e; sm += e;
        }
      sm += __shfl_xor(sm, 16, 64);
      sm += __shfl_xor(sm, 32, 64);
      float inv = 1.f / sm;
#pragma unroll
      for (int mt = 0; mt < 4; ++mt)
#pragma unroll
        for (int jj = 0; jj < 4; ++jj) z[mt][jj] *= inv;
    }

    // colsum partials
#pragma unroll
    for (int mt = 0; mt < 4; ++mt)
#pragma unroll
      for (int jj = 0; jj < 4; ++jj) {
        float v = z[mt][jj];
        v += __shfl_xor(v, 1, 64); v += __shfl_xor(v, 2, 64);
        v += __shfl_xor(v, 4, 64); v += __shfl_xor(v, 8, 64);
        if (l15 == 0) cpart[w][mt * 16 + g * 4 + jj] = v;
      }

    // z -> zT LDS; last step also -> zA global
#pragma unroll
    for (int mt = 0; mt < 4; ++mt)
#pragma unroll
      for (int jj = 0; jj < 4; ++jj) {
        int k = mt * 16 + g * 4 + jj;
        int tl = w * 16 + l15;
        f16 h = (f16)z[mt][jj];
        zT_s[k * RPB + (((tl >> 3) ^ (k & 7)) << 3) + (tl & 7)] = h;
        if (st == 9) zA[((size_t)b * L_ + l0 + tl) * K_ + k] = h;
      }
    __syncthreads();

    if (t < K_) {
      float s = 0.f;
#pragma unroll
      for (int q = 0; q < 4; ++q) s += cpart[q][t];
      cp[(size_t)chn * (B_ * K_) + b * K_ + t] = s;
    }

    // ---- phase3: part[k][c] = z^T . xT (wave owns c-quarter w*64)
    {
      f32x4 a3[4][4];
#pragma unroll
      for (int mt = 0; mt < 4; ++mt)
#pragma unroll
        for (int nt = 0; nt < 4; ++nt)
#pragma unroll
          for (int j = 0; j < 4; ++j) a3[mt][nt][j] = 0.f;
      int cb = w * 64;
#pragma unroll
      for (int ks = 0; ks < 2; ++ks) {
        f16x8 az[4], bx[4];
#pragma unroll
        for (int mt = 0; mt < 4; ++mt)
          az[mt] = *(const f16x8*)(zT_s + (mt * 16 + l15) * RPB + (((ks * 4 + g) ^ (l15 & 7)) << 3));
#pragma unroll
        for (int nt = 0; nt < 4; ++nt) {
          int c = cb + nt * 16 + l15;
          bx[nt] = *(const f16x8*)(xtile + c * RPB + (((ks * 4 + g) ^ (c & 7)) << 3));
        }
#pragma unroll
        for (int mt = 0; mt < 4; ++mt)
#pragma unroll
          for (int nt = 0; nt < 4; ++nt)
            a3[mt][nt] = __builtin_amdgcn_mfma_f32_16x16x32_f16(az[mt], bx[nt], a3[mt][nt], 0, 0, 0);
      }
      f16* pp = part + (((size_t)chn * B_ + b) * K_) * C_;
#pragma unroll
      for (int mt = 0; mt < 4; ++mt)
#pragma unroll
        for (int nt = 0; nt < 4; ++nt)
#pragma unroll
          for (int jj = 0; jj < 4; ++jj)
            pp[(size_t)(mt * 16 + g * 4 + jj) * C_ + cb + nt * 16 + l15] = (f16)a3[mt][nt][jj];
    }

    gbar(bar, GRID_EM * (++ph));      // part + cp published

    // ---- mufin (blocks 0..255): (mb, mkg) = old k_mufin mapping
    if (bid < 256) {
      int mb = bid >> 4, mkg = bid & 15;
      int kr = t >> 6, c4 = t & 63, k = mkg * 4 + kr;
      float a0 = 0.f, a1 = 0.f, a2 = 0.f, a3v = 0.f;
#pragma unroll
      for (int c2 = 0; c2 < NCH; ++c2) {
        f16x4 p = *(const f16x4*)(part + (((size_t)c2 * B_ + mb) * K_ + k) * C_ + c4 * 4);
        a0 += (float)p[0]; a1 += (float)p[1]; a2 += (float)p[2]; a3v += (float)p[3];
      }
      float zs = 0.f;
#pragma unroll
      for (int c2 = 0; c2 < NCH; ++c2) zs += cp[(size_t)c2 * (B_ * K_) + mb * K_ + k];
      float sc = 1.f / (EPSF + zs);
      a0 *= sc; a1 *= sc; a2 *= sc; a3v *= sc;
      float ssq = a0 * a0 + a1 * a1 + a2 * a2 + a3v * a3v;
#pragma unroll
      for (int off = 32; off >= 1; off >>= 1) ssq += __shfl_xor(ssq, off, 64);
      float inv = 1.f / (EPSF + sqrtf(ssq));
      a0 *= inv; a1 *= inv; a2 *= inv; a3v *= inv;
      size_t base = (size_t)(mb * K_ + k) * C_ + c4 * 4;
      f16x4 hm; hm[0] = (f16)a0; hm[1] = (f16)a1; hm[2] = (f16)a2; hm[3] = (f16)a3v;
      *(f16x4*)(muF + base) = hm;
      if (st == 9) {
        if (c4 == 0) zsA[mb * K_ + k] = zs;
        *(float4*)(outmu + base) = make_float4(a0, a1, a2, a3v);
        muT[((size_t)mb * C_ + c4 * 4 + 0) * K_ + k] = hm[0];
        muT[((size_t)mb * C_ + c4 * 4 + 1) * K_ + k] = hm[1];
        muT[((size_t)mb * C_ + c4 * 4 + 2) * K_ + k] = hm[2];
        muT[((size_t)mb * C_ + c4 * 4 + 3) * K_ + k] = hm[3];
      }
    }

    gbar(bar, GRID_EM * (++ph));      // muF (step st+1) published
  }

  // ---- post phase: new_z with mu_10 -> attn (replaces k_em<false,true>+k_attn)
#pragma unroll
  for (int q = 0; q < 8; ++q) {
    int s = q * 256 + t, k = s >> 5, sl = s & 31;
    gload16(muF + (size_t)b * (K_ * C_) + k * C_ + ((sl ^ (k & 15)) << 3), mu_s + s * 8);
  }
  asm volatile("s_waitcnt vmcnt(0)" ::: "memory");
  __syncthreads();

  {
    f32x4 acc[4];
#pragma unroll
    for (int mt = 0; mt < 4; ++mt)
#pragma unroll
      for (int j = 0; j < 4; ++j) acc[mt][j] = 0.f;
#pragma unroll
    for (int ck = 0; ck < 8; ++ck) {
#pragma unroll
      for (int mt = 0; mt < 4; ++mt) {
        f16x8 a = *(const f16x8*)(mu_s + (mt * 16 + l15) * C_ + (((ck * 4 + g) ^ l15) << 3));
        acc[mt] = __builtin_amdgcn_mfma_f32_16x16x32_f16(a, xfr[ck], acc[mt], 0, 0, 0);
      }
    }
    float mx = acc[0][0];
#pragma unroll
    for (int mt = 0; mt < 4; ++mt)
#pragma unroll
      for (int jj = 0; jj < 4; ++jj) mx = fmaxf(mx, acc[mt][jj]);
    mx = fmaxf(mx, __shfl_xor(mx, 16, 64));
    mx = fmaxf(mx, __shfl_xor(mx, 32, 64));
    float sm = 0.f;
#pragma unroll
    for (int mt = 0; mt < 4; ++mt)
#pragma unroll
      for (int jj = 0; jj < 4; ++jj) {
        float e = __expf(acc[mt][jj] - mx);
        z[mt][jj] = e; sm += e;
      }
    sm += __shfl_xor(sm, 16, 64);
    sm += __shfl_xor(sm, 32, 64);
    float inv = 1.f / sm;
#pragma unroll
    for (int mt = 0; mt < 4; ++mt)
#pragma unroll
      for (int jj = 0; jj < 4; ++jj) z[mt][jj] *= inv;
  }
  // colsum partials -> cp
#pragma unroll
  for (int mt = 0; mt < 4; ++mt)
#pragma unroll
    for (int jj = 0; jj < 4; ++jj) {
      float v = z[mt][jj];
      v += __shfl_xor(v, 1, 64); v += __shfl_xor(v, 2, 64);
      v += __shfl_xor(v, 4, 64); v += __shfl_xor(v, 8, 64);
      if (l15 == 0) cpart[w][mt * 16 + g * 4 + jj] = v;
    }
  __syncthreads();
  if (t < K_) {
    float s = 0.f;
#pragma unroll
    for (int q = 0; q < 4; ++q) s += cpart[q][t];
    cp[(size_t)chn * (B_ * K_) + b * K_ + t] = s;
  }

  gbar(bar, GRID_EM * (++ph));        // cp (new_z colsums) published

  if (t < K_) {
    float s = 0.f;
#pragma unroll
    for (int c2 = 0; c2 < NCH; ++c2) s += cp[(size_t)c2 * (B_ * K_) + b * K_ + t];
    cpart[0][t] = 1.f / (EPSF + s);
  }
  __syncthreads();
#pragma unroll
  for (int mt = 0; mt < 4; ++mt)
#pragma unroll
    for (int jj = 0; jj < 4; ++jj) {
      int k = mt * 16 + g * 4 + jj;
      attnout[((size_t)b * K_ + k) * L_ + l0 + w * 16 + l15] = z[mt][jj] * cpart[0][k];
    }
}

// ---------------------------------------------------------------- k_mlp (r11 verbatim)
constexpr int W1S_OFF  = 0;
constexpr int W2S_OFF  = 65536;
constexpr int BNS_OFF  = 131072;
constexpr int ZINV_OFF = 139264;
constexpr int POOL_SZ  = 139520;

__global__ __launch_bounds__(512, 2) void k_mlp(
    const f16* __restrict__ zA,
    const f16* __restrict__ muT,
    const float* __restrict__ zsA,
    const unsigned short* __restrict__ w1fr,
    const unsigned short* __restrict__ w2fr,
    const f16* __restrict__ bnshH, const float* __restrict__ b2,
    float* __restrict__ outr)
{
  __shared__ __align__(16) char pool[POOL_SZ];
  unsigned short* w1s = (unsigned short*)(pool + W1S_OFF);
  unsigned short* w2s = (unsigned short*)(pool + W2S_OFF);
  f16* bns_s          = (f16*)(pool + BNS_OFF);
  float* zinv_s       = (float*)(pool + ZINV_OFF);
  f16* muT_s          = (f16*)(pool + W1S_OFF + 32768);
  f16* z_s            = (f16*)(pool + W2S_OFF + 32768);

  int t = threadIdx.x, w = t >> 6, lane = t & 63, l31 = lane & 31, l5 = lane >> 5;
  int rb = blockIdx.x * 128, b = rb >> 11, l0 = rb & 2047;
  int tt = w & 3, ih = w >> 2;

#define STAGE(ic, buf)                                                    \
  {                                                                       \
    _Pragma("unroll")                                                     \
    for (int q = 0; q < 4; ++q) {                                         \
      int d2 = q * 512 + t;                                               \
      gload16(w1fr + (size_t)(ic) * 16384 + d2 * 8,                       \
              w1s + (size_t)(buf) * 16384 + d2 * 8);                      \
    }                                                                     \
    _Pragma("unroll")                                                     \
    for (int q = 0; q < 4; ++q) {                                         \
      int d2 = q * 512 + t;                                               \
      gload16(w2fr + (size_t)(ic) * 16384 + d2 * 8,                       \
              w2s + (size_t)(buf) * 16384 + d2 * 8);                      \
    }                                                                     \
  }

  if (t < K_) zinv_s[t] = 1.f / (EPSF + zsA[b * K_ + t]);
  __builtin_amdgcn_sched_barrier(0);
#pragma unroll
  for (int q = 0; q < 4; ++q) {
    int s = q * 512 + t, c = s >> 3, sl = s & 7;
    gload16(muT + ((size_t)b * C_ + c) * K_ + ((sl ^ (c & 7)) << 3), muT_s + s * 8);
  }
#pragma unroll
  for (int q = 0; q < 2; ++q) {
    int s = q * 512 + t, tok = s >> 3, sl = s & 7;
    gload16(zA + ((size_t)b * L_ + l0 + tok) * K_ + ((sl ^ (tok & 7)) << 3), z_s + s * 8);
  }
  gload16(bnshH + t * 8, bns_s + t * 8);
  __builtin_amdgcn_sched_barrier(0);
  STAGE(0, 0);
  __builtin_amdgcn_sched_barrier(0);
  asm volatile("s_waitcnt vmcnt(8) lgkmcnt(0)" ::: "memory");
  __builtin_amdgcn_s_barrier();
  __builtin_amdgcn_sched_barrier(0);

  bf16x8 rc[16];
  {
    f16x8 bz[4];
#pragma unroll
    for (int kk = 0; kk < 4; ++kk) {
      int tok = tt * 32 + l31;
      f16x8 zr = *(const f16x8*)(z_s + tok * 64 + (((kk * 2 + l5) ^ (tok & 7)) << 3));
      f16x8 sc2;
#pragma unroll
      for (int e = 0; e < 8; ++e)
        sc2[e] = (f16)((float)zr[e] * zinv_s[kk * 16 + l5 * 8 + e]);
      bz[kk] = sc2;
    }
    f32x16 d[8];
#pragma unroll
    for (int m = 0; m < 8; ++m)
#pragma unroll
      for (int r = 0; r < 16; ++r) d[m][r] = 0.f;
#pragma unroll
    for (int kk = 0; kk < 4; ++kk) {
#pragma unroll
      for (int m = 0; m < 8; ++m) {
        int c = m * 32 + l31;
        f16x8 am = *(const f16x8*)(muT_s + c * 64 + (((kk * 2 + l5) ^ (c & 7)) << 3));
        d[m] = __builtin_amdgcn_mfma_f32_32x32x16_f16(am, bz[kk], d[m], 0, 0, 0);
      }
    }
    union Uf { unsigned u[4]; bf16x8 v; } rcU[16];
#pragma unroll
    for (int m = 0; m < 8; ++m)
#pragma unroll
      for (int q = 0; q < 8; ++q) {
        unsigned u = (unsigned)f2bf(d[m][2 * q]) | ((unsigned)f2bf(d[m][2 * q + 1]) << 16);
        rcU[2 * m + (q >> 2)].u[q & 3] = u;
      }
#pragma unroll
    for (int ks = 0; ks < 16; ++ks) rc[ks] = rcU[ks].v;
  }
  asm volatile("s_waitcnt lgkmcnt(0)" ::: "memory");
  __builtin_amdgcn_s_barrier();
  __builtin_amdgcn_sched_barrier(0);

  f32x16 acc2[8];
#pragma unroll
  for (int ot = 0; ot < 8; ++ot)
#pragma unroll
    for (int r = 0; r < 16; ++r) acc2[ot][r] = 0.f;

  const unsigned short* p1base = w1s + ih * 8192 + l5 * 256 + l31 * 8;
  const unsigned short* p2base = w2s + ih * 8192 + l5 * 2048 + l31 * 8;

  for (int ic = 0; ic < 64; ++ic) {
    int cur = ic & 1;
    asm volatile("s_waitcnt vmcnt(0)" ::: "memory");
    __builtin_amdgcn_s_barrier();
    __builtin_amdgcn_sched_barrier(0);
    if (ic < 63) STAGE(ic + 1, cur ^ 1);
    __builtin_amdgcn_sched_barrier(0);

    f32x16 h0, h1;
#pragma unroll
    for (int r = 0; r < 16; ++r) { h0[r] = 0.f; h1[r] = 0.f; }
    const unsigned short* p1 = p1base + cur * 16384;
    __builtin_amdgcn_s_setprio(1);
#pragma unroll
    for (int ks = 0; ks < 16; ++ks) {
      bf16x8 a1 = *(const bf16x8*)(p1 + ks * 512);
      if (ks & 1) h1 = __builtin_amdgcn_mfma_f32_32x32x16_bf16(a1, rc[ks], h1, 0, 0, 0);
      else        h0 = __builtin_amdgcn_mfma_f32_32x32x16_bf16(a1, rc[ks], h0, 0, 0, 0);
    }
    __builtin_amdgcn_s_setprio(0);
#pragma unroll
    for (int r = 0; r < 16; ++r) h0[r] += h1[r];

    f16x4 bnv[4];
#pragma unroll
    for (int q = 0; q < 4; ++q)
      bnv[q] = *(const f16x4*)(bns_s + ic * 64 + ih * 32 + 8 * q + 4 * l5);
    unsigned pk[8];
#pragma unroll
    for (int q = 0; q < 4; ++q) {
#pragma unroll
      for (int pr = 0; pr < 2; ++pr) {
        int r0 = q * 4 + pr * 2;
        float v0 = fmaxf(h0[r0]     + (float)bnv[q][pr * 2],     0.f);
        float v1 = fmaxf(h0[r0 + 1] + (float)bnv[q][pr * 2 + 1], 0.f);
        pk[q * 2 + pr] = (unsigned)f2bf(v0) | ((unsigned)f2bf(v1) << 16);
      }
    }
    union Uf { unsigned u[4]; bf16x8 v; };
    Uf bfr0, bfr1;
#pragma unroll
    for (int m = 0; m < 4; ++m) { bfr0.u[m] = pk[m]; bfr1.u[m] = pk[4 + m]; }

    const unsigned short* p2 = p2base + cur * 16384;
    __builtin_amdgcn_s_setprio(1);
#pragma unroll
    for (int s = 0; s < 2; ++s) {
      bf16x8 bfv = s ? bfr1.v : bfr0.v;
#pragma unroll
      for (int ot = 0; ot < 8; ++ot) {
        bf16x8 a2 = *(const bf16x8*)(p2 + s * 4096 + ot * 256);
        acc2[ot] = __builtin_amdgcn_mfma_f32_32x32x16_bf16(a2, bfv, acc2[ot], 0, 0, 0);
      }
    }
    __builtin_amdgcn_s_setprio(0);
  }
#undef STAGE

  __syncthreads();
  float* red = (float*)pool;
  if (ih == 1) {
#pragma unroll
    for (int ot = 0; ot < 8; ++ot)
#pragma unroll
      for (int r = 0; r < 16; ++r)
        red[((tt * 8 + ot) * 16 + r) * 64 + lane] = acc2[ot][r];
  }
  __syncthreads();
  if (ih == 0) {
    int tok = rb + tt * 32 + l31;
#pragma unroll
    for (int ot = 0; ot < 8; ++ot) {
#pragma unroll
      for (int r = 0; r < 16; ++r)
        acc2[ot][r] += red[((tt * 8 + ot) * 16 + r) * 64 + lane];
#pragma unroll
      for (int q = 0; q < 4; ++q) {
        int o = ot * 32 + 8 * q + 4 * l5;
        float4 bias = *(const float4*)(b2 + o);
        f32x4 v;
        v[0] = acc2[ot][q * 4 + 0] + bias.x;
        v[1] = acc2[ot][q * 4 + 1] + bias.y;
        v[2] = acc2[ot][q * 4 + 2] + bias.z;
        v[3] = acc2[ot][q * 4 + 3] + bias.w;
        *(f32x4*)(outr + (size_t)tok * C_ + o) = v;
      }
    }
  }
}

// ---------------------------------------------------------------- launch
extern "C" void kernel_launch(void* const* d_in, const int* in_sizes, int n_in,
                              void* d_out, int out_size, void* d_ws, size_t ws_size,
                              hipStream_t stream)
{
  const float* x     = (const float*)d_in[0];
  const float* mu0   = (const float*)d_in[2];
  const float* w1    = (const float*)d_in[3];
  const float* b1    = (const float*)d_in[4];
  const float* gamma = (const float*)d_in[5];
  const float* beta  = (const float*)d_in[6];
  const float* bmean = (const float*)d_in[7];
  const float* bvar  = (const float*)d_in[8];
  const float* w2    = (const float*)d_in[9];
  const float* b2    = (const float*)d_in[10];
  float* out = (float*)d_out;

  char* wsb = (char*)d_ws;
  f16* part = (f16*)(wsb + 0);                                  // 16,777,216 B
  f16* zA   = (f16*)(wsb + 16777216);                           // 4,194,304
  f16* xf   = (f16*)(wsb + 20971520);                           // 16,777,216
  f16* xTf  = (f16*)(wsb + 37748736);                           // 16,777,216
  unsigned short* w1fr = (unsigned short*)(wsb + 54525952);     // 2,097,152
  unsigned short* w2fr = (unsigned short*)(wsb + 56623104);     // 2,097,152
  f16*   muF   = (f16*)(wsb + 58720256);                        // 524,288
  f16*   muT   = (f16*)(wsb + 59244544);                        // 524,288
  f16*   bnshH = (f16*)(wsb + 59768832);                        // 8,192
  float* cpA   = (float*)(wsb + 59777024);                      // 131,072
  float* zsA   = (float*)(wsb + 59908096);                      // 4,096
  unsigned* bar = (unsigned*)(wsb + 59912192);                  // 64 B (~60MB total)

  hipMemsetAsync(bar, 0, 64, stream);
  k_prext<<<6144, 256, 0, stream>>>(x, w1, w2, gamma, beta, bmean, bvar, b1, mu0,
                                    w1fr, w2fr, bnshH, muF, xf, xTf);
  k_emfused<<<GRID_EM, 256, 0, stream>>>(xf, xTf, muF, muT, zA, cpA, part, zsA,
                                         out, out + 262144, bar);
  k_mlp<<<256, 512, 0, stream>>>(zA, muT, zsA, w1fr, w2fr, bnshH, b2, out + 2359296);
}

// Round 13
// 323.213 us; speedup vs baseline: 9.2851x; 9.2851x over previous
//
#include <hip/hip_runtime.h>

constexpr int B_ = 16, L_ = 2048, C_ = 256, K_ = 64, INNER_ = 4096;
constexpr int NCH = 16;          // L-chunks
constexpr int RPB = 128;         // rows per k_em block
#define EPSF 1e-6f

typedef __attribute__((ext_vector_type(8)))  short bf16x8;
typedef __attribute__((ext_vector_type(4)))  float f32x4;
typedef __attribute__((ext_vector_type(16))) float f32x16;
typedef _Float16 f16;
typedef __attribute__((ext_vector_type(8))) _Float16 f16x8;
typedef __attribute__((ext_vector_type(4))) _Float16 f16x4;

__device__ __forceinline__ unsigned short f2bf(float f) {
  union { float f; unsigned u; } v; v.f = f;
  unsigned r = v.u + 0x7fffu + ((v.u >> 16) & 1u);   // RNE
  return (unsigned short)(r >> 16);
}

__device__ __forceinline__ void gload16(const void* src, void* lds) {
  __builtin_amdgcn_global_load_lds(
      (const __attribute__((address_space(1))) unsigned*)src,
      (__attribute__((address_space(3))) unsigned*)lds, 16, 0, 0);
}

// ---------------------------------------------------------------- k_prext
// merged k_pre (bid<4096) + k_xT (bid>=4096)  [r12, proven]
__global__ __launch_bounds__(256) void k_prext(
    const float* __restrict__ x,
    const float* __restrict__ w1, const float* __restrict__ w2,
    const float* __restrict__ gamma, const float* __restrict__ beta,
    const float* __restrict__ bmean, const float* __restrict__ bvar,
    const float* __restrict__ b1, const float* __restrict__ mu0,
    unsigned short* __restrict__ w1fr, unsigned short* __restrict__ w2fr,
    f16* __restrict__ bnshH, f16* __restrict__ muF,
    f16* __restrict__ xf, f16* __restrict__ xTf)
{
  __shared__ float ts[64][65];
  int bid = blockIdx.x, t = threadIdx.x;
  if (bid < 4096) {
    int i = bid * 256 + t;     // covers 1048576
    if (i < INNER_ * C_) {
      int j = i & 7, l31 = (i >> 3) & 31;
      { // w1fr: sigma k-perm; l5 bit 8, ks 9-12, ih 13, ic 14+
        int l5 = (i >> 8) & 1, ks = (i >> 9) & 15, ih = (i >> 13) & 1, ic = i >> 14;
        int r1 = ic * 64 + ih * 32 + l31;
        int c1 = ks * 16 + 4 * l5 + 8 * (j >> 2) + (j & 3);
        float sc = gamma[r1] * rsqrtf(bvar[r1] + 1e-5f);
        w1fr[i] = f2bf(w1[(size_t)r1 * C_ + c1] * sc);
      }
      { // w2fr: sigma k-perm; ot 8-10, l5 11, g 12+
        int ot = (i >> 8) & 7, l5 = (i >> 11) & 1, g = i >> 12;
        int o = ot * 32 + l31;
        int ii = g * 16 + 4 * l5 + 8 * (j >> 2) + (j & 3);
        w2fr[i] = f2bf(w2[(size_t)o * INNER_ + ii]);
      }
    }
    if (i < B_ * K_ * C_) muF[i] = (f16)mu0[i & (K_ * C_ - 1)];
    if (i < INNER_) {
      float sc = gamma[i] * rsqrtf(bvar[i] + 1e-5f);
      bnshH[i] = (f16)fmaf(b1[i] - bmean[i], sc, beta[i]);
    }
  } else {
    int b2 = bid - 4096;
    int l0 = (b2 & 31) * 64, c0 = ((b2 >> 5) & 3) * 64, b = b2 >> 7;
    for (int p = 0; p < 16; ++p) {
      int e = t + p * 256, i = e >> 6, j = e & 63;
      float vv = x[((size_t)b * L_ + l0 + i) * C_ + c0 + j];
      ts[i][j] = vv;
      xf[((size_t)b * L_ + l0 + i) * C_ + c0 + j] = (f16)vv;
    }
    __syncthreads();
    for (int p = 0; p < 16; ++p) {
      int e = t + p * 256, i = e >> 6, j = e & 63;
      xTf[((size_t)b * C_ + c0 + i) * L_ + l0 + j] = (f16)ts[j][i];
    }
  }
}

// ---------------------------------------------------------------- k_em
// r5 version (validated @356µs round): 512 thr / 8 waves, RPB=128, NCH=16.
template<bool DO_MU, bool WRITE_Z>
__global__ __launch_bounds__(512, 2) void k_em(
    const f16* __restrict__ xf,    // [B][L][C]
    const f16* __restrict__ xTf,   // [B][C][L]
    const f16* __restrict__ muF,   // [B][K][C]
    f16* __restrict__ zout,        // [B][L][K]
    float* __restrict__ cp,        // [NCH][B*K]
    f16* __restrict__ part)        // [NCH][B][K][C]
{
  __shared__ f16 mu_s[K_ * C_];     // 32KB, slot ^ (k&15)
  __shared__ f16 zT_s[K_ * RPB];    // 16KB, slot ^ (k&15)
  __shared__ f16 xtile[C_ * RPB];   // 64KB, slot ^ (c&7)
  __shared__ float cpart[8][K_];

  int t = threadIdx.x, b = blockIdx.y, chn = blockIdx.x, l0 = chn * RPB;
  int w = t >> 6, lane = t & 63, l15 = lane & 15, g = lane >> 4;

  // stage mu (2048 slots, 4/thread) -- OLDEST vmem
#pragma unroll
  for (int q = 0; q < 4; ++q) {
    int s = q * 512 + t, k = s >> 5, sl = s & 31;
    gload16(muF + (size_t)b * (K_ * C_) + k * C_ + ((sl ^ (k & 15)) << 3), mu_s + s * 8);
  }
  __builtin_amdgcn_sched_barrier(0);
  // xf rows into regs BEFORE the xtile stage so xf waits don't drain xtile
  f16x8 xfr[8];
  const f16* xr = xf + ((size_t)b * L_ + l0 + w * 16 + l15) * C_ + g * 8;
#pragma unroll
  for (int ck = 0; ck < 8; ++ck) xfr[ck] = *(const f16x8*)(xr + ck * 32);
  __builtin_amdgcn_sched_barrier(0);
  if (DO_MU) {
    // stage xT tile (4096 slots, 8/thread) -- NEWEST, stays in flight
#pragma unroll
    for (int q = 0; q < 8; ++q) {
      int s = q * 512 + t, c = s >> 4, sl = s & 15;
      gload16(xTf + (size_t)(b * C_ + c) * L_ + l0 + ((sl ^ (c & 7)) << 3), xtile + s * 8);
    }
    __builtin_amdgcn_sched_barrier(0);
    asm volatile("s_waitcnt vmcnt(16)" ::: "memory");   // mu landed; xf+xtile in flight
  } else {
    asm volatile("s_waitcnt vmcnt(8)" ::: "memory");    // mu landed; xf in flight
  }
  __builtin_amdgcn_s_barrier();
  __builtin_amdgcn_sched_barrier(0);

  // ---- phase1: S^T[k][tok], wave w owns tok tile w
  f32x4 acc[4];
#pragma unroll
  for (int mt = 0; mt < 4; ++mt)
#pragma unroll
    for (int j = 0; j < 4; ++j) acc[mt][j] = 0.f;
#pragma unroll
  for (int ck = 0; ck < 8; ++ck) {
#pragma unroll
    for (int mt = 0; mt < 4; ++mt) {
      f16x8 a = *(const f16x8*)(mu_s + (mt * 16 + l15) * C_ + (((ck * 4 + g) ^ l15) << 3));
      acc[mt] = __builtin_amdgcn_mfma_f32_16x16x32_f16(a, xfr[ck], acc[mt], 0, 0, 0);
    }
  }

  // ---- phase2: softmax over k
  float z[4][4];
  {
    float mx = acc[0][0];
#pragma unroll
    for (int mt = 0; mt < 4; ++mt)
#pragma unroll
      for (int jj = 0; jj < 4; ++jj) mx = fmaxf(mx, acc[mt][jj]);
    mx = fmaxf(mx, __shfl_xor(mx, 16, 64));
    mx = fmaxf(mx, __shfl_xor(mx, 32, 64));
    float sm = 0.f;
#pragma unroll
    for (int mt = 0; mt < 4; ++mt)
#pragma unroll
      for (int jj = 0; jj < 4; ++jj) {
        float e = __expf(acc[mt][jj] - mx);
        z[mt][jj] = e; sm += e;
      }
    sm += __shfl_xor(sm, 16, 64);
    sm += __shfl_xor(sm, 32, 64);
    float inv = 1.f / sm;
#pragma unroll
    for (int mt = 0; mt < 4; ++mt)
#pragma unroll
      for (int jj = 0; jj < 4; ++jj) z[mt][jj] *= inv;
  }

  // colsum partial over this wave's 16 toks
#pragma unroll
  for (int mt = 0; mt < 4; ++mt)
#pragma unroll
    for (int jj = 0; jj < 4; ++jj) {
      float v = z[mt][jj];
      v += __shfl_xor(v, 1, 64); v += __shfl_xor(v, 2, 64);
      v += __shfl_xor(v, 4, 64); v += __shfl_xor(v, 8, 64);
      if (l15 == 0) cpart[w][mt * 16 + g * 4 + jj] = v;
    }

  // z -> zT LDS (swizzled) and/or z global
#pragma unroll
  for (int mt = 0; mt < 4; ++mt)
#pragma unroll
    for (int jj = 0; jj < 4; ++jj) {
      int k = mt * 16 + g * 4 + jj;
      int tl = w * 16 + l15;
      f16 h = (f16)z[mt][jj];
      if (DO_MU)   zT_s[k * RPB + (((tl >> 3) ^ (k & 15)) << 3) + (tl & 7)] = h;
      if (WRITE_Z) zout[((size_t)b * L_ + l0 + tl) * K_ + k] = h;
    }
  __syncthreads();   // zT/cpart ready; drains vmcnt -> xtile landed

  if (t < K_) {
    float s = 0.f;
#pragma unroll
    for (int q = 0; q < 8; ++q) s += cpart[q][t];
    cp[(size_t)chn * (B_ * K_) + b * K_ + t] = s;
  }

  // ---- phase3: part[k][c] = z^T . xT, wave w owns c-slice w*32..+32
  if (DO_MU) {
    f32x4 a3[4][2];
#pragma unroll
    for (int mt = 0; mt < 4; ++mt)
#pragma unroll
      for (int nt = 0; nt < 2; ++nt)
#pragma unroll
        for (int j = 0; j < 4; ++j) a3[mt][nt][j] = 0.f;
    int cb = w * 32;
#pragma unroll
    for (int ks = 0; ks < 4; ++ks) {
      f16x8 az[4], bx[2];
#pragma unroll
      for (int mt = 0; mt < 4; ++mt)
        az[mt] = *(const f16x8*)(zT_s + (mt * 16 + l15) * RPB + (((ks * 4 + g) ^ l15) << 3));
#pragma unroll
      for (int nt = 0; nt < 2; ++nt) {
        int c = cb + nt * 16 + l15;
        bx[nt] = *(const f16x8*)(xtile + c * RPB + (((ks * 4 + g) ^ (c & 7)) << 3));
      }
#pragma unroll
      for (int mt = 0; mt < 4; ++mt)
#pragma unroll
        for (int nt = 0; nt < 2; ++nt)
          a3[mt][nt] = __builtin_amdgcn_mfma_f32_16x16x32_f16(az[mt], bx[nt], a3[mt][nt], 0, 0, 0);
    }
    f16* pp = part + (((size_t)chn * B_ + b) * K_) * C_;
#pragma unroll
    for (int mt = 0; mt < 4; ++mt)
#pragma unroll
      for (int nt = 0; nt < 2; ++nt)
#pragma unroll
        for (int jj = 0; jj < 4; ++jj)
          pp[(size_t)(mt * 16 + g * 4 + jj) * C_ + cb + nt * 16 + l15] = (f16)a3[mt][nt][jj];
  }
}

// ---------------------------------------------------------------- k_mufin (NCH=16)
template<bool LAST>
__global__ __launch_bounds__(256) void k_mufin(
    const f16* __restrict__ part, const float* __restrict__ cp,
    f16* __restrict__ muF, f16* __restrict__ muT,
    float* __restrict__ zsA, float* __restrict__ outmu)
{
  int b = blockIdx.x >> 4, kg = blockIdx.x & 15, t = threadIdx.x;
  int kr = t >> 6, c4 = t & 63, k = kg * 4 + kr;
  float a0 = 0.f, a1 = 0.f, a2 = 0.f, a3 = 0.f;
#pragma unroll
  for (int chn = 0; chn < NCH; ++chn) {
    f16x4 p = *(const f16x4*)(part + (((size_t)chn * B_ + b) * K_ + k) * C_ + c4 * 4);
    a0 += (float)p[0]; a1 += (float)p[1]; a2 += (float)p[2]; a3 += (float)p[3];
  }
  float zs = 0.f;
#pragma unroll
  for (int chn = 0; chn < NCH; ++chn) zs += cp[(size_t)chn * (B_ * K_) + b * K_ + k];
  float sc = 1.f / (EPSF + zs);
  a0 *= sc; a1 *= sc; a2 *= sc; a3 *= sc;
  float ssq = a0 * a0 + a1 * a1 + a2 * a2 + a3 * a3;
#pragma unroll
  for (int off = 32; off >= 1; off >>= 1) ssq += __shfl_xor(ssq, off, 64);
  float inv = 1.f / (EPSF + sqrtf(ssq));
  a0 *= inv; a1 *= inv; a2 *= inv; a3 *= inv;
  size_t base = (size_t)(b * K_ + k) * C_ + c4 * 4;
  f16x4 hm; hm[0] = (f16)a0; hm[1] = (f16)a1; hm[2] = (f16)a2; hm[3] = (f16)a3;
  *(f16x4*)(muF + base) = hm;
  if (c4 == 0) zsA[b * K_ + k] = zs;
  if (LAST) {
    *(float4*)(outmu + base) = make_float4(a0, a1, a2, a3);
    muT[((size_t)b * C_ + c4 * 4 + 0) * K_ + k] = hm[0];
    muT[((size_t)b * C_ + c4 * 4 + 1) * K_ + k] = hm[1];
    muT[((size_t)b * C_ + c4 * 4 + 2) * K_ + k] = hm[2];
    muT[((size_t)b * C_ + c4 * 4 + 3) * K_ + k] = hm[3];
  }
}

// ---------------------------------------------------------------- k_attn (NCH=16)
__global__ __launch_bounds__(256) void k_attn(
    const f16* __restrict__ zB, const float* __restrict__ cpB, float* __restrict__ attn)
{
  __shared__ float zt[64][68];
  __shared__ float inv_s[K_];
  int b = blockIdx.y, l0 = blockIdx.x * 64, t = threadIdx.x;
  if (t < K_) {
    float zs = 0.f;
#pragma unroll
    for (int chn = 0; chn < NCH; ++chn) zs += cpB[(size_t)chn * (B_ * K_) + b * K_ + t];
    inv_s[t] = 1.f / (EPSF + zs);
  }
  for (int p = 0; p < 16; ++p) {
    int e = t + p * 256, lo = e >> 6, k = e & 63;
    zt[lo][k] = (float)zB[((size_t)b * L_ + l0 + lo) * K_ + k];
  }
  __syncthreads();
  int lo = t & 63, kb = t >> 6;
  for (int p = 0; p < 16; ++p) {
    int k = kb * 16 + p;
    attn[((size_t)b * K_ + k) * L_ + l0 + lo] = zt[lo][k] * inv_s[k];
  }
}

// ---------------------------------------------------------------- k_mlp (r11 verbatim)
constexpr int W1S_OFF  = 0;
constexpr int W2S_OFF  = 65536;
constexpr int BNS_OFF  = 131072;
constexpr int ZINV_OFF = 139264;
constexpr int POOL_SZ  = 139520;

__global__ __launch_bounds__(512, 2) void k_mlp(
    const f16* __restrict__ zA,
    const f16* __restrict__ muT,
    const float* __restrict__ zsA,
    const unsigned short* __restrict__ w1fr,
    const unsigned short* __restrict__ w2fr,
    const f16* __restrict__ bnshH, const float* __restrict__ b2,
    float* __restrict__ outr)
{
  __shared__ __align__(16) char pool[POOL_SZ];
  unsigned short* w1s = (unsigned short*)(pool + W1S_OFF);
  unsigned short* w2s = (unsigned short*)(pool + W2S_OFF);
  f16* bns_s          = (f16*)(pool + BNS_OFF);
  float* zinv_s       = (float*)(pool + ZINV_OFF);
  f16* muT_s          = (f16*)(pool + W1S_OFF + 32768);
  f16* z_s            = (f16*)(pool + W2S_OFF + 32768);

  int t = threadIdx.x, w = t >> 6, lane = t & 63, l31 = lane & 31, l5 = lane >> 5;
  int rb = blockIdx.x * 128, b = rb >> 11, l0 = rb & 2047;
  int tt = w & 3, ih = w >> 2;

#define STAGE(ic, buf)                                                    \
  {                                                                       \
    _Pragma("unroll")                                                     \
    for (int q = 0; q < 4; ++q) {                                         \
      int d2 = q * 512 + t;                                               \
      gload16(w1fr + (size_t)(ic) * 16384 + d2 * 8,                       \
              w1s + (size_t)(buf) * 16384 + d2 * 8);                      \
    }                                                                     \
    _Pragma("unroll")                                                     \
    for (int q = 0; q < 4; ++q) {                                         \
      int d2 = q * 512 + t;                                               \
      gload16(w2fr + (size_t)(ic) * 16384 + d2 * 8,                       \
              w2s + (size_t)(buf) * 16384 + d2 * 8);                      \
    }                                                                     \
  }

  if (t < K_) zinv_s[t] = 1.f / (EPSF + zsA[b * K_ + t]);
  __builtin_amdgcn_sched_barrier(0);
#pragma unroll
  for (int q = 0; q < 4; ++q) {
    int s = q * 512 + t, c = s >> 3, sl = s & 7;
    gload16(muT + ((size_t)b * C_ + c) * K_ + ((sl ^ (c & 7)) << 3), muT_s + s * 8);
  }
#pragma unroll
  for (int q = 0; q < 2; ++q) {
    int s = q * 512 + t, tok = s >> 3, sl = s & 7;
    gload16(zA + ((size_t)b * L_ + l0 + tok) * K_ + ((sl ^ (tok & 7)) << 3), z_s + s * 8);
  }
  gload16(bnshH + t * 8, bns_s + t * 8);
  __builtin_amdgcn_sched_barrier(0);
  STAGE(0, 0);
  __builtin_amdgcn_sched_barrier(0);
  asm volatile("s_waitcnt vmcnt(8) lgkmcnt(0)" ::: "memory");
  __builtin_amdgcn_s_barrier();
  __builtin_amdgcn_sched_barrier(0);

  bf16x8 rc[16];
  {
    f16x8 bz[4];
#pragma unroll
    for (int kk = 0; kk < 4; ++kk) {
      int tok = tt * 32 + l31;
      f16x8 zr = *(const f16x8*)(z_s + tok * 64 + (((kk * 2 + l5) ^ (tok & 7)) << 3));
      f16x8 sc2;
#pragma unroll
      for (int e = 0; e < 8; ++e)
        sc2[e] = (f16)((float)zr[e] * zinv_s[kk * 16 + l5 * 8 + e]);
      bz[kk] = sc2;
    }
    f32x16 d[8];
#pragma unroll
    for (int m = 0; m < 8; ++m)
#pragma unroll
      for (int r = 0; r < 16; ++r) d[m][r] = 0.f;
#pragma unroll
    for (int kk = 0; kk < 4; ++kk) {
#pragma unroll
      for (int m = 0; m < 8; ++m) {
        int c = m * 32 + l31;
        f16x8 am = *(const f16x8*)(muT_s + c * 64 + (((kk * 2 + l5) ^ (c & 7)) << 3));
        d[m] = __builtin_amdgcn_mfma_f32_32x32x16_f16(am, bz[kk], d[m], 0, 0, 0);
      }
    }
    union Uf { unsigned u[4]; bf16x8 v; } rcU[16];
#pragma unroll
    for (int m = 0; m < 8; ++m)
#pragma unroll
      for (int q = 0; q < 8; ++q) {
        unsigned u = (unsigned)f2bf(d[m][2 * q]) | ((unsigned)f2bf(d[m][2 * q + 1]) << 16);
        rcU[2 * m + (q >> 2)].u[q & 3] = u;
      }
#pragma unroll
    for (int ks = 0; ks < 16; ++ks) rc[ks] = rcU[ks].v;
  }
  asm volatile("s_waitcnt lgkmcnt(0)" ::: "memory");
  __builtin_amdgcn_s_barrier();
  __builtin_amdgcn_sched_barrier(0);

  f32x16 acc2[8];
#pragma unroll
  for (int ot = 0; ot < 8; ++ot)
#pragma unroll
    for (int r = 0; r < 16; ++r) acc2[ot][r] = 0.f;

  const unsigned short* p1base = w1s + ih * 8192 + l5 * 256 + l31 * 8;
  const unsigned short* p2base = w2s + ih * 8192 + l5 * 2048 + l31 * 8;

  for (int ic = 0; ic < 64; ++ic) {
    int cur = ic & 1;
    asm volatile("s_waitcnt vmcnt(0)" ::: "memory");
    __builtin_amdgcn_s_barrier();
    __builtin_amdgcn_sched_barrier(0);
    if (ic < 63) STAGE(ic + 1, cur ^ 1);
    __builtin_amdgcn_sched_barrier(0);

    f32x16 h0, h1;
#pragma unroll
    for (int r = 0; r < 16; ++r) { h0[r] = 0.f; h1[r] = 0.f; }
    const unsigned short* p1 = p1base + cur * 16384;
    __builtin_amdgcn_s_setprio(1);
#pragma unroll
    for (int ks = 0; ks < 16; ++ks) {
      bf16x8 a1 = *(const bf16x8*)(p1 + ks * 512);
      if (ks & 1) h1 = __builtin_amdgcn_mfma_f32_32x32x16_bf16(a1, rc[ks], h1, 0, 0, 0);
      else        h0 = __builtin_amdgcn_mfma_f32_32x32x16_bf16(a1, rc[ks], h0, 0, 0, 0);
    }
    __builtin_amdgcn_s_setprio(0);
#pragma unroll
    for (int r = 0; r < 16; ++r) h0[r] += h1[r];

    f16x4 bnv[4];
#pragma unroll
    for (int q = 0; q < 4; ++q)
      bnv[q] = *(const f16x4*)(bns_s + ic * 64 + ih * 32 + 8 * q + 4 * l5);
    unsigned pk[8];
#pragma unroll
    for (int q = 0; q < 4; ++q) {
#pragma unroll
      for (int pr = 0; pr < 2; ++pr) {
        int r0 = q * 4 + pr * 2;
        float v0 = fmaxf(h0[r0]     + (float)bnv[q][pr * 2],     0.f);
        float v1 = fmaxf(h0[r0 + 1] + (float)bnv[q][pr * 2 + 1], 0.f);
        pk[q * 2 + pr] = (unsigned)f2bf(v0) | ((unsigned)f2bf(v1) << 16);
      }
    }
    union Uf { unsigned u[4]; bf16x8 v; };
    Uf bfr0, bfr1;
#pragma unroll
    for (int m = 0; m < 4; ++m) { bfr0.u[m] = pk[m]; bfr1.u[m] = pk[4 + m]; }

    const unsigned short* p2 = p2base + cur * 16384;
    __builtin_amdgcn_s_setprio(1);
#pragma unroll
    for (int s = 0; s < 2; ++s) {
      bf16x8 bfv = s ? bfr1.v : bfr0.v;
#pragma unroll
      for (int ot = 0; ot < 8; ++ot) {
        bf16x8 a2 = *(const bf16x8*)(p2 + s * 4096 + ot * 256);
        acc2[ot] = __builtin_amdgcn_mfma_f32_32x32x16_bf16(a2, bfv, acc2[ot], 0, 0, 0);
      }
    }
    __builtin_amdgcn_s_setprio(0);
  }
#undef STAGE

  __syncthreads();
  float* red = (float*)pool;
  if (ih == 1) {
#pragma unroll
    for (int ot = 0; ot < 8; ++ot)
#pragma unroll
      for (int r = 0; r < 16; ++r)
        red[((tt * 8 + ot) * 16 + r) * 64 + lane] = acc2[ot][r];
  }
  __syncthreads();
  if (ih == 0) {
    int tok = rb + tt * 32 + l31;
#pragma unroll
    for (int ot = 0; ot < 8; ++ot) {
#pragma unroll
      for (int r = 0; r < 16; ++r)
        acc2[ot][r] += red[((tt * 8 + ot) * 16 + r) * 64 + lane];
#pragma unroll
      for (int q = 0; q < 4; ++q) {
        int o = ot * 32 + 8 * q + 4 * l5;
        float4 bias = *(const float4*)(b2 + o);
        f32x4 v;
        v[0] = acc2[ot][q * 4 + 0] + bias.x;
        v[1] = acc2[ot][q * 4 + 1] + bias.y;
        v[2] = acc2[ot][q * 4 + 2] + bias.z;
        v[3] = acc2[ot][q * 4 + 3] + bias.w;
        *(f32x4*)(outr + (size_t)tok * C_ + o) = v;
      }
    }
  }
}

// ---------------------------------------------------------------- launch
extern "C" void kernel_launch(void* const* d_in, const int* in_sizes, int n_in,
                              void* d_out, int out_size, void* d_ws, size_t ws_size,
                              hipStream_t stream)
{
  const float* x     = (const float*)d_in[0];
  const float* mu0   = (const float*)d_in[2];
  const float* w1    = (const float*)d_in[3];
  const float* b1    = (const float*)d_in[4];
  const float* gamma = (const float*)d_in[5];
  const float* beta  = (const float*)d_in[6];
  const float* bmean = (const float*)d_in[7];
  const float* bvar  = (const float*)d_in[8];
  const float* w2    = (const float*)d_in[9];
  const float* b2    = (const float*)d_in[10];
  float* out = (float*)d_out;

  char* wsb = (char*)d_ws;
  f16* part = (f16*)(wsb + 0);                                  // 8,388,608 B
  f16* zB   = part;                                             // alias (dead after last mufin)
  f16* zA   = (f16*)(wsb + 8388608);                            // 4,194,304
  f16* xf   = (f16*)(wsb + 12582912);                           // 16,777,216
  f16* xTf  = (f16*)(wsb + 29360128);                           // 16,777,216
  unsigned short* w1fr = (unsigned short*)(wsb + 46137344);     // 2,097,152
  unsigned short* w2fr = (unsigned short*)(wsb + 48234496);     // 2,097,152
  f16*   muF   = (f16*)(wsb + 50331648);                        // 524,288
  f16*   muT   = (f16*)(wsb + 50855936);                        // 524,288
  f16*   bnshH = (f16*)(wsb + 51380224);                        // 8,192
  float* cpA   = (float*)(wsb + 51388416);                      // 65,536
  float* cpB   = (float*)(wsb + 51453952);                      // 65,536
  float* zsA   = (float*)(wsb + 51519488);                      // 4,096  (~51.5MB)

  k_prext<<<6144, 256, 0, stream>>>(x, w1, w2, gamma, beta, bmean, bvar, b1, mu0,
                                    w1fr, w2fr, bnshH, muF, xf, xTf);

  for (int s = 0; s < 10; ++s) {
    if (s == 9) k_em<true, true ><<<dim3(NCH, 16), 512, 0, stream>>>(xf, xTf, muF, zA, cpA, part);
    else        k_em<true, false><<<dim3(NCH, 16), 512, 0, stream>>>(xf, xTf, muF, zA, cpA, part);
    if (s == 9) k_mufin<true ><<<256, 256, 0, stream>>>(part, cpA, muF, muT, zsA, out);
    else        k_mufin<false><<<256, 256, 0, stream>>>(part, cpA, muF, muT, zsA, out);
  }
  // new_z with final mu (no mu-update; zB overlays dead part buffer)
  k_em<false, true><<<dim3(NCH, 16), 512, 0, stream>>>(xf, xTf, muF, zB, cpB, part);
  k_attn<<<dim3(32, 16), 256, 0, stream>>>(zB, cpB, out + 262144);
  k_mlp<<<256, 512, 0, stream>>>(zA, muT, zsA, w1fr, w2fr, bnshH, b2, out + 2359296);
}